// Round 12
// baseline (1131.719 us; speedup 1.0000x reference)
//
#include <hip/hip_runtime.h>
#include <hip/hip_bf16.h>

#define M_BATCH 65536
#define K_IN    1024
#define N_OUT   256

#define BM  128
#define BK  32
#define NKT (K_IN / BK)   // 32
#define LDK 40            // 32 + 8 shorts padding: 16B-aligned, low-conflict
#define TAU 0.0625f

typedef __attribute__((ext_vector_type(8))) short short8;   // 8 bf16
typedef __attribute__((ext_vector_type(4))) short short4v;
typedef __attribute__((ext_vector_type(4))) float f32x4;

__device__ inline short f2bf(float f) {          // RNE via HW cvt
    __hip_bfloat16 h = __float2bfloat16(f);
    return __builtin_bit_cast(short, h);
}
__device__ inline float bf2f(short s) {
    unsigned u = ((unsigned)(unsigned short)s) << 16;
    return __builtin_bit_cast(float, u);
}

// ---- kernel 0: one-time W f32 -> bf16 (exact: W ternary) into d_ws ----
__global__ __launch_bounds__(256) void wconv(const float* __restrict__ w,
                                             short* __restrict__ wbf) {
    const int i = blockIdx.x * 256 + threadIdx.x;    // float4 index, 65536 total
    const float4 v = ((const float4*)w)[i];
    short4v h;
    h.x = f2bf(v.x); h.y = f2bf(v.y); h.z = f2bf(v.z); h.w = f2bf(v.w);
    ((short4v*)wbf)[i] = h;
}

// ---- main: split-bf16 MFMA GEMM, BN=256 (x streamed once), BK=32,
// double-buffered LDS (1 barrier/K-step), depth-2 register prefetch.
// Band cells |t+0.5| < TAU -> C3-exact recompute (r8/r9/r10/r11-verified).
__global__ __launch_bounds__(512, 4) void binlin_mfma3(const float* __restrict__ x,
                                                       const short* __restrict__ wbf,
                                                       const float* __restrict__ w,
                                                       const float* __restrict__ bias,
                                                       const float* __restrict__ sign,
                                                       float* __restrict__ out) {
    __shared__ __align__(16) short smem[40960];      // 80 KB
    short* AhB = smem;                               // [2][128][40]
    short* AlB = smem + 10240;                       // [2][128][40]
    short* BhB = smem + 20480;                       // [2][256][40]

    const int tid  = threadIdx.x;    // 0..511
    const int lane = tid & 63;
    const int wid  = tid >> 6;       // 8 waves: 2(m) x 4(n)
    const int wm   = wid >> 2;
    const int wn   = wid & 3;
    const int l15  = lane & 15;
    const int l4   = lane >> 4;
    const int m0   = blockIdx.x * BM;

    // x staging: 1024 float4 / 512 thr = 2 each. idx -> row=idx>>3, kc=(idx&7)*4
    const int xrow0 = tid >> 3;          // 0..63  (and +64)
    const int xkc   = (tid & 7) * 4;
    // w staging: 1024 short8 / 512 thr = 2 each. idx -> row=idx>>2, kc=(idx&3)*8
    const int wrow0 = tid >> 2;          // 0..127 (and +128)
    const int wkc   = (tid & 3) * 8;

    float4 xr[2][2];                     // [set][q]
    short8 wr[2][2];

    f32x4 acc[4][4];
#pragma unroll
    for (int i = 0; i < 4; ++i)
#pragma unroll
        for (int j = 0; j < 4; ++j) acc[i][j] = (f32x4){0.f, 0.f, 0.f, 0.f};

#define LOADT(S, KT)                                                            \
    {                                                                           \
        xr[S][0] = *(const float4*)(x + (size_t)(m0 + xrow0) * K_IN + (KT) * BK + xkc);      \
        xr[S][1] = *(const float4*)(x + (size_t)(m0 + xrow0 + 64) * K_IN + (KT) * BK + xkc); \
        wr[S][0] = *(const short8*)(wbf + (size_t)wrow0 * K_IN + (KT) * BK + wkc);           \
        wr[S][1] = *(const short8*)(wbf + (size_t)(wrow0 + 128) * K_IN + (KT) * BK + wkc);   \
    }

#define STORET(S, B)                                                            \
    {                                                                           \
        _Pragma("unroll")                                                       \
        for (int q = 0; q < 2; ++q) {                                           \
            const float4 v = xr[S][q];                                          \
            short4v h, l;                                                       \
            h.x = f2bf(v.x); h.y = f2bf(v.y); h.z = f2bf(v.z); h.w = f2bf(v.w); \
            l.x = f2bf(v.x - bf2f(h.x)); l.y = f2bf(v.y - bf2f(h.y));           \
            l.z = f2bf(v.z - bf2f(h.z)); l.w = f2bf(v.w - bf2f(h.w));           \
            const int ro = (B) * 5120 + (xrow0 + q * 64) * LDK + xkc;           \
            *(short4v*)&AhB[ro] = h;                                            \
            *(short4v*)&AlB[ro] = l;                                            \
        }                                                                       \
        *(short8*)&BhB[(B) * 10240 + wrow0 * LDK + wkc] = wr[S][0];             \
        *(short8*)&BhB[(B) * 10240 + (wrow0 + 128) * LDK + wkc] = wr[S][1];     \
    }

    LOADT(0, 0)
    STORET(0, 0)
    LOADT(1, 1)
    __syncthreads();

    for (int kt = 0; kt < NKT; ++kt) {
        if (kt + 2 < NKT) LOADT(kt & 1, kt + 2)      // in flight over this iter

        const int b = kt & 1;
        short8 bfr[4];
#pragma unroll
        for (int ni = 0; ni < 4; ++ni)
            bfr[ni] = *(const short8*)&BhB[b * 10240 + (wn * 64 + ni * 16 + l15) * LDK + l4 * 8];
#pragma unroll
        for (int mi = 0; mi < 4; ++mi) {
            const int ro = b * 5120 + (wm * 64 + mi * 16 + l15) * LDK + l4 * 8;
            const short8 ahi = *(const short8*)&AhB[ro];
            const short8 alo = *(const short8*)&AlB[ro];
#pragma unroll
            for (int ni = 0; ni < 4; ++ni) {
                acc[mi][ni] = __builtin_amdgcn_mfma_f32_16x16x32_bf16(
                    ahi, bfr[ni], acc[mi][ni], 0, 0, 0);
                acc[mi][ni] = __builtin_amdgcn_mfma_f32_16x16x32_bf16(
                    alo, bfr[ni], acc[mi][ni], 0, 0, 0);
            }
        }

        if (kt + 1 < NKT) STORET((kt + 1) & 1, (kt + 1) & 1)
        __syncthreads();
    }

    // ---- epilogue: decide (+ C3-exact band fixup) -> u8 LDS -> coalesced out
    unsigned char* dec = (unsigned char*)smem;       // 32 KB overlay
#pragma unroll
    for (int ni = 0; ni < 4; ++ni) {
        const int n = wn * 64 + ni * 16 + l15;
        const float b = bias[n];
        const float s = sign[n];
#pragma unroll
        for (int mi = 0; mi < 4; ++mi) {
            const int ml = wm * 64 + mi * 16 + l4 * 4;
#pragma unroll
            for (int j = 0; j < 4; ++j) {
                const float t = (acc[mi][ni][j] + b) * s;
                unsigned char d;
                if (fabsf(t + 0.5f) < TAU) {
                    // C3-exact: kc=512 panels, one sequential f32 chain each
                    const float* xr_ = x + (size_t)(m0 + ml + j) * K_IN;
                    const float* wr_ = w + (size_t)n * K_IN;
                    float a0 = 0.f, a1 = 0.f;
                    for (int k4 = 0; k4 < 128; ++k4) {
                        const float4 xv0 = *(const float4*)(xr_ + k4 * 4);
                        const float4 wv0 = *(const float4*)(wr_ + k4 * 4);
                        const float4 xv1 = *(const float4*)(xr_ + 512 + k4 * 4);
                        const float4 wv1 = *(const float4*)(wr_ + 512 + k4 * 4);
                        a0 = fmaf(xv0.x, wv0.x, a0); a1 = fmaf(xv1.x, wv1.x, a1);
                        a0 = fmaf(xv0.y, wv0.y, a0); a1 = fmaf(xv1.y, wv1.y, a1);
                        a0 = fmaf(xv0.z, wv0.z, a0); a1 = fmaf(xv1.z, wv1.z, a1);
                        a0 = fmaf(xv0.w, wv0.w, a0); a1 = fmaf(xv1.w, wv1.w, a1);
                    }
                    const float tt = ((a0 + a1) + b) * s;
                    d = (tt >= -0.5f) ? 1 : 0;
                } else {
                    d = (t >= -0.5f) ? 1 : 0;
                }
                dec[(ml + j) * N_OUT + n] = d;
            }
        }
    }
    __syncthreads();

#pragma unroll
    for (int it = 0; it < 16; ++it) {
        const int f   = it * 512 + tid;   // float4 index in 128x256 tile
        const int row = f >> 6;
        const int c4  = f & 63;
        const uchar4 dv = *(const uchar4*)&dec[row * N_OUT + c4 * 4];
        *(float4*)(out + (size_t)(m0 + row) * N_OUT + c4 * 4) =
            make_float4((float)dv.x, (float)dv.y, (float)dv.z, (float)dv.w);
    }
}

extern "C" void kernel_launch(void* const* d_in, const int* in_sizes, int n_in,
                              void* d_out, int out_size, void* d_ws, size_t ws_size,
                              hipStream_t stream) {
    const float* x    = (const float*)d_in[0];
    const float* w    = (const float*)d_in[1];
    const float* bias = (const float*)d_in[2];
    const float* sign = (const float*)d_in[3];

    if (n_in >= 4 && in_sizes[0] != M_BATCH * K_IN) {   // defensive no-op
        const float* small[2] = {nullptr, nullptr};
        int nsmall = 0;
        for (int i = 0; i < 4; ++i) {
            if (in_sizes[i] == M_BATCH * K_IN)      x = (const float*)d_in[i];
            else if (in_sizes[i] == N_OUT * K_IN)   w = (const float*)d_in[i];
            else if (nsmall < 2) small[nsmall++] = (const float*)d_in[i];
        }
        if (nsmall == 2) { bias = small[0]; sign = small[1]; }
    }

    short* wbf = (short*)d_ws;                       // 512 KB
    float* out = (float*)d_out;

    wconv<<<256, 256, 0, stream>>>(w, wbf);
    binlin_mfma3<<<M_BATCH / BM, 512, 0, stream>>>(x, wbf, w, bias, sign, out);
}

// Round 13
// 444.747 us; speedup vs baseline: 2.5446x; 2.5446x over previous
//
#include <hip/hip_runtime.h>
#include <hip/hip_bf16.h>

#define M_BATCH 65536
#define K_IN    1024
#define N_OUT   256

#define BM  128
#define BK  32
#define NKT (K_IN / BK)   // 32
#define LDK 40            // 32 + 8 shorts padding: 16B-aligned, low-conflict
#define TAU 0.0625f

// LDS short-offsets (all compile-time literals)
#define A_BUF 5120        // 128*40 shorts per A buffer
#define B_BUF 10240       // 256*40 shorts per B buffer
#define AH0 0
#define AH1 (A_BUF)
#define AL0 (2 * A_BUF)
#define AL1 (3 * A_BUF)
#define BH0 (4 * A_BUF)
#define BH1 (4 * A_BUF + B_BUF)

typedef __attribute__((ext_vector_type(8))) short short8;   // 8 bf16
typedef __attribute__((ext_vector_type(4))) short short4v;
typedef __attribute__((ext_vector_type(4))) float f32x4;

__device__ inline short f2bf(float f) {          // RNE via HW cvt
    __hip_bfloat16 h = __float2bfloat16(f);
    return __builtin_bit_cast(short, h);
}
__device__ inline float bf2f(short s) {
    unsigned u = ((unsigned)(unsigned short)s) << 16;
    return __builtin_bit_cast(float, u);
}

// ---- kernel 0: one-time W f32 -> bf16 (exact: W ternary) into d_ws ----
__global__ __launch_bounds__(256) void wconv(const float* __restrict__ w,
                                             short* __restrict__ wbf) {
    const int i = blockIdx.x * 256 + threadIdx.x;    // float4 index, 65536 total
    const float4 v = ((const float4*)w)[i];
    short4v h;
    h.x = f2bf(v.x); h.y = f2bf(v.y); h.z = f2bf(v.z); h.w = f2bf(v.w);
    ((short4v*)wbf)[i] = h;
}

// ---- main: split-bf16 MFMA GEMM, BN=256 (x streamed once), BK=32,
// double-buffered LDS (1 barrier/K-step), depth-2 prefetch with NAMED
// register sets + literal buffer offsets (r12's runtime-indexed arrays
// spilled to scratch: VGPR 64, WRITE_SIZE 319MB -> rule #20).
// Band cells |t+0.5| < TAU -> C3-exact recompute (r8..r12-verified).
__global__ __launch_bounds__(512) void binlin_mfma4(const float* __restrict__ x,
                                                    const short* __restrict__ wbf,
                                                    const float* __restrict__ w,
                                                    const float* __restrict__ bias,
                                                    const float* __restrict__ sign,
                                                    float* __restrict__ out) {
    __shared__ __align__(16) short smem[40960];      // 80 KB

    const int tid  = threadIdx.x;    // 0..511
    const int lane = tid & 63;
    const int wid  = tid >> 6;       // 8 waves: 2(m) x 4(n)
    const int wm   = wid >> 2;
    const int wn   = wid & 3;
    const int l15  = lane & 15;
    const int l4   = lane >> 4;
    const int m0   = blockIdx.x * BM;

    // x staging: 1024 float4 / 512 thr = 2 each (rows xrow0, xrow0+64)
    const int xrow0 = tid >> 3;          // 0..63
    const int xkc   = (tid & 7) * 4;
    // w staging: 1024 short8 / 512 thr = 2 each (rows wrow0, wrow0+128)
    const int wrow0 = tid >> 2;          // 0..127
    const int wkc   = (tid & 3) * 8;

    float4 xA0, xA1, xB0, xB1;           // named prefetch sets (no runtime idx)
    short8 wA0, wA1, wB0, wB1;

    f32x4 acc[4][4];
#pragma unroll
    for (int i = 0; i < 4; ++i)
#pragma unroll
        for (int j = 0; j < 4; ++j) acc[i][j] = (f32x4){0.f, 0.f, 0.f, 0.f};

#define LOADX(X0, X1, KT)                                                       \
    X0 = *(const float4*)(x + (size_t)(m0 + xrow0) * K_IN + (KT) * BK + xkc);   \
    X1 = *(const float4*)(x + (size_t)(m0 + xrow0 + 64) * K_IN + (KT) * BK + xkc);
#define LOADW(W0, W1, KT)                                                       \
    W0 = *(const short8*)(wbf + (size_t)wrow0 * K_IN + (KT) * BK + wkc);        \
    W1 = *(const short8*)(wbf + (size_t)(wrow0 + 128) * K_IN + (KT) * BK + wkc);
#define STOREX(X0, X1, AH, AL)                                                  \
    {                                                                           \
        short4v h, l;                                                           \
        h.x = f2bf(X0.x); h.y = f2bf(X0.y); h.z = f2bf(X0.z); h.w = f2bf(X0.w); \
        l.x = f2bf(X0.x - bf2f(h.x)); l.y = f2bf(X0.y - bf2f(h.y));             \
        l.z = f2bf(X0.z - bf2f(h.z)); l.w = f2bf(X0.w - bf2f(h.w));             \
        *(short4v*)&smem[(AH) + xrow0 * LDK + xkc] = h;                         \
        *(short4v*)&smem[(AL) + xrow0 * LDK + xkc] = l;                         \
        h.x = f2bf(X1.x); h.y = f2bf(X1.y); h.z = f2bf(X1.z); h.w = f2bf(X1.w); \
        l.x = f2bf(X1.x - bf2f(h.x)); l.y = f2bf(X1.y - bf2f(h.y));             \
        l.z = f2bf(X1.z - bf2f(h.z)); l.w = f2bf(X1.w - bf2f(h.w));             \
        *(short4v*)&smem[(AH) + (xrow0 + 64) * LDK + xkc] = h;                  \
        *(short4v*)&smem[(AL) + (xrow0 + 64) * LDK + xkc] = l;                  \
    }
#define STOREW(W0, W1, BH)                                                      \
    *(short8*)&smem[(BH) + wrow0 * LDK + wkc] = W0;                             \
    *(short8*)&smem[(BH) + (wrow0 + 128) * LDK + wkc] = W1;
#define MFMA_STEP(AH, AL, BH)                                                   \
    {                                                                           \
        short8 bfr[4];                                                          \
        _Pragma("unroll")                                                       \
        for (int ni = 0; ni < 4; ++ni)                                          \
            bfr[ni] = *(const short8*)&smem[(BH) + (wn * 64 + ni * 16 + l15) * LDK + l4 * 8]; \
        _Pragma("unroll")                                                       \
        for (int mi = 0; mi < 4; ++mi) {                                        \
            const int ro = (wm * 64 + mi * 16 + l15) * LDK + l4 * 8;            \
            const short8 ahi = *(const short8*)&smem[(AH) + ro];                \
            const short8 alo = *(const short8*)&smem[(AL) + ro];                \
            _Pragma("unroll")                                                   \
            for (int ni = 0; ni < 4; ++ni) {                                    \
                acc[mi][ni] = __builtin_amdgcn_mfma_f32_16x16x32_bf16(          \
                    ahi, bfr[ni], acc[mi][ni], 0, 0, 0);                        \
                acc[mi][ni] = __builtin_amdgcn_mfma_f32_16x16x32_bf16(          \
                    alo, bfr[ni], acc[mi][ni], 0, 0, 0);                        \
            }                                                                   \
        }                                                                       \
    }

    // prologue: tile0 -> buf0; tile1 -> setB (stored at end of first even half)
    LOADX(xA0, xA1, 0)
    LOADW(wA0, wA1, 0)
    STOREX(xA0, xA1, AH0, AL0)
    STOREW(wA0, wA1, BH0)
    LOADX(xB0, xB1, 1)
    LOADW(wB0, wB1, 1)
    __syncthreads();

    for (int it = 0; it < 16; ++it) {
        const int kt = it * 2;
        // ---- even half: compute tile kt from buf0
        if (it < 15) {                       // setA <- tile kt+2 (2 iters in flight)
            LOADX(xA0, xA1, kt + 2)
            LOADW(wA0, wA1, kt + 2)
        }
        MFMA_STEP(AH0, AL0, BH0)
        STOREX(xB0, xB1, AH1, AL1)           // setB (tile kt+1) -> buf1
        STOREW(wB0, wB1, BH1)
        __syncthreads();

        // ---- odd half: compute tile kt+1 from buf1
        if (it < 15) {                       // setB <- tile kt+3
            LOADX(xB0, xB1, kt + 3)
            LOADW(wB0, wB1, kt + 3)
        }
        MFMA_STEP(AH1, AL1, BH1)
        if (it < 15) {
            STOREX(xA0, xA1, AH0, AL0)       // setA (tile kt+2) -> buf0
            STOREW(wA0, wA1, BH0)
        }
        __syncthreads();
    }

    // ---- epilogue: decide (+ C3-exact band fixup) -> u8 LDS -> coalesced out
    unsigned char* dec = (unsigned char*)smem;       // 32 KB overlay
#pragma unroll
    for (int ni = 0; ni < 4; ++ni) {
        const int n = wn * 64 + ni * 16 + l15;
        const float b = bias[n];
        const float s = sign[n];
#pragma unroll
        for (int mi = 0; mi < 4; ++mi) {
            const int ml = wm * 64 + mi * 16 + l4 * 4;
#pragma unroll
            for (int j = 0; j < 4; ++j) {
                const float t = (acc[mi][ni][j] + b) * s;
                unsigned char d;
                if (fabsf(t + 0.5f) < TAU) {
                    // C3-exact: kc=512 panels, one sequential f32 chain each
                    const float* xr_ = x + (size_t)(m0 + ml + j) * K_IN;
                    const float* wr_ = w + (size_t)n * K_IN;
                    float a0 = 0.f, a1 = 0.f;
                    for (int k4 = 0; k4 < 128; ++k4) {
                        const float4 xv0 = *(const float4*)(xr_ + k4 * 4);
                        const float4 wv0 = *(const float4*)(wr_ + k4 * 4);
                        const float4 xv1 = *(const float4*)(xr_ + 512 + k4 * 4);
                        const float4 wv1 = *(const float4*)(wr_ + 512 + k4 * 4);
                        a0 = fmaf(xv0.x, wv0.x, a0); a1 = fmaf(xv1.x, wv1.x, a1);
                        a0 = fmaf(xv0.y, wv0.y, a0); a1 = fmaf(xv1.y, wv1.y, a1);
                        a0 = fmaf(xv0.z, wv0.z, a0); a1 = fmaf(xv1.z, wv1.z, a1);
                        a0 = fmaf(xv0.w, wv0.w, a0); a1 = fmaf(xv1.w, wv1.w, a1);
                    }
                    const float tt = ((a0 + a1) + b) * s;
                    d = (tt >= -0.5f) ? 1 : 0;
                } else {
                    d = (t >= -0.5f) ? 1 : 0;
                }
                dec[(ml + j) * N_OUT + n] = d;
            }
        }
    }
    __syncthreads();

#pragma unroll
    for (int it = 0; it < 16; ++it) {
        const int f   = it * 512 + tid;   // float4 index in 128x256 tile
        const int row = f >> 6;
        const int c4  = f & 63;
        const uchar4 dv = *(const uchar4*)&dec[row * N_OUT + c4 * 4];
        *(float4*)(out + (size_t)(m0 + row) * N_OUT + c4 * 4) =
            make_float4((float)dv.x, (float)dv.y, (float)dv.z, (float)dv.w);
    }
}

extern "C" void kernel_launch(void* const* d_in, const int* in_sizes, int n_in,
                              void* d_out, int out_size, void* d_ws, size_t ws_size,
                              hipStream_t stream) {
    const float* x    = (const float*)d_in[0];
    const float* w    = (const float*)d_in[1];
    const float* bias = (const float*)d_in[2];
    const float* sign = (const float*)d_in[3];

    if (n_in >= 4 && in_sizes[0] != M_BATCH * K_IN) {   // defensive no-op
        const float* small[2] = {nullptr, nullptr};
        int nsmall = 0;
        for (int i = 0; i < 4; ++i) {
            if (in_sizes[i] == M_BATCH * K_IN)      x = (const float*)d_in[i];
            else if (in_sizes[i] == N_OUT * K_IN)   w = (const float*)d_in[i];
            else if (nsmall < 2) small[nsmall++] = (const float*)d_in[i];
        }
        if (nsmall == 2) { bias = small[0]; sign = small[1]; }
    }

    short* wbf = (short*)d_ws;                       // 512 KB
    float* out = (float*)d_out;

    wconv<<<256, 256, 0, stream>>>(w, wbf);
    binlin_mfma4<<<M_BATCH / BM, 512, 0, stream>>>(x, wbf, w, bias, sign, out);
}